// Round 2
// baseline (91.905 us; speedup 1.0000x reference)
//
#include <hip/hip_runtime.h>

#define OUT_CH 128
#define WAVES_PER_BLOCK 4

// One wave (64 lanes) per edge. segment_ids sorted ascending, tokens in {0..3}.
// Per wave: binary-search [lower_bound(e), lower_bound(e+1)), coalesced token
// read, packed 4x16-bit register histogram, 64-lane butterfly reduce, then
// each lane writes 2 channels (float2) of out[e] = (counts . emb) / max(tot,1).
__global__ __launch_bounds__(WAVES_PER_BLOCK * 64)
void edge_fused_kernel(const int* __restrict__ tokens,
                       const int* __restrict__ segids,
                       const float* __restrict__ emb,
                       float* __restrict__ out,
                       int T, int E) {
    const int lane = threadIdx.x & 63;
    const int wid  = threadIdx.x >> 6;
    const int e = blockIdx.x * WAVES_PER_BLOCK + wid;
    if (e >= E) return;

    // Two interleaved lower_bound searches over [0, T]:
    //   start = first idx with segids[idx] >= e
    //   end   = first idx with segids[idx] >= e+1
    // lo/hi are wave-uniform; the two loads per iteration are independent (ILP 2).
    int lo0 = 0, hi0 = T;
    int lo1 = 0, hi1 = T;
    while ((lo0 < hi0) | (lo1 < hi1)) {
        int mid0 = (lo0 + hi0) >> 1;
        int mid1 = (lo1 + hi1) >> 1;
        int v0 = (lo0 < hi0) ? segids[mid0] : 0x7FFFFFFF;
        int v1 = (lo1 < hi1) ? segids[mid1] : 0x7FFFFFFF;
        if (lo0 < hi0) { if (v0 < e)     lo0 = mid0 + 1; else hi0 = mid0; }
        if (lo1 < hi1) { if (v1 < e + 1) lo1 = mid1 + 1; else hi1 = mid1; }
    }
    const int start = lo0, end = lo1;

    // Coalesced token read: lanes stride 1, wave strides 64.
    // Packed histogram: 4 counts in 16-bit fields of a u64.
    // Max segment length ~350 << 65535: no overflow.
    unsigned long long acc = 0;
    for (int k = start + lane; k < end; k += 64) {
        acc += 1ull << (tokens[k] << 4);
    }
    // Butterfly reduction across all 64 lanes (every lane ends with the total).
    #pragma unroll
    for (int m = 32; m > 0; m >>= 1) {
        acc += __shfl_xor(acc, m, 64);
    }

    const float c0 = (float)(acc & 0xFFFFull);
    const float c1 = (float)((acc >> 16) & 0xFFFFull);
    const float c2 = (float)((acc >> 32) & 0xFFFFull);
    const float c3 = (float)((acc >> 48) & 0xFFFFull);
    const float tot = c0 + c1 + c2 + c3;
    const float inv = 1.0f / fmaxf(tot, 1.0f);

    // Each lane produces channels [2*lane, 2*lane+1] -> coalesced float2 store.
    const int c = lane << 1;
    const float2 e0 = *(const float2*)(emb + 0 * OUT_CH + c);
    const float2 e1 = *(const float2*)(emb + 1 * OUT_CH + c);
    const float2 e2 = *(const float2*)(emb + 2 * OUT_CH + c);
    const float2 e3 = *(const float2*)(emb + 3 * OUT_CH + c);

    float2 r;
    r.x = (c0 * e0.x + c1 * e1.x + c2 * e2.x + c3 * e3.x) * inv;
    r.y = (c0 * e0.y + c1 * e1.y + c2 * e2.y + c3 * e3.y) * inv;
    *(float2*)(out + (size_t)e * OUT_CH + c) = r;
}

extern "C" void kernel_launch(void* const* d_in, const int* in_sizes, int n_in,
                              void* d_out, int out_size, void* d_ws, size_t ws_size,
                              hipStream_t stream) {
    // inputs (setup_inputs order):
    // 0: overlap_similarity f32 [E]   (unused)
    // 1: overlap_length     f32 [E]   (unused)
    // 2: tokens             i32 [T]
    // 3: segment_ids        i32 [T]   (sorted)
    // 4: embedding          f32 [4,128]
    // 5: n_edges            i32 [1]   (device scalar; derive E from out_size)
    const int* tokens = (const int*)d_in[2];
    const int* segids = (const int*)d_in[3];
    const float* emb  = (const float*)d_in[4];
    float* out = (float*)d_out;

    const int T = in_sizes[2];
    const int E = out_size / OUT_CH;

    const int blocks = (E + WAVES_PER_BLOCK - 1) / WAVES_PER_BLOCK;
    edge_fused_kernel<<<blocks, WAVES_PER_BLOCK * 64, 0, stream>>>(
        tokens, segids, emb, out, T, E);
}

// Round 3
// 82.611 us; speedup vs baseline: 1.1125x; 1.1125x over previous
//
#include <hip/hip_runtime.h>

#define OUT_CH 128
#define WAVES_PER_BLOCK 4

// Kernel A: segment boundary finder. segids sorted ascending in [0, E).
// Writes starts[0..E] (int, in d_ws): starts[e] = first token index of edge e,
// starts[E] = T. Every entry written exactly once (covers empty edges), so no
// dependence on d_ws initial contents (it's poisoned 0xAA).
__global__ void seg_starts_kernel(const int* __restrict__ segids,
                                  int* __restrict__ starts,
                                  int T, int E) {
    int i = blockIdx.x * blockDim.x + threadIdx.x;  // handles tokens [4i, 4i+4)
    int k = i << 2;
    if (k >= T) return;
    const int4 s4 = *(const int4*)(segids + k);
    int s[5] = {s4.x, s4.y, s4.z, s4.w, 0};
    s[4] = (k + 4 < T) ? segids[k + 4] : E;   // sentinel: past-the-end edge id
    if (k == 0) {
        for (int q = 0; q <= s4.x; ++q) starts[q] = 0;
    }
#pragma unroll
    for (int j = 0; j < 4; ++j) {
        // boundary between token k+j (edge s[j]) and k+j+1 (edge s[j+1]);
        // each q in (s[j], s[j+1]] is owned by exactly this thread/j.
        for (int q = s[j] + 1; q <= s[j + 1]; ++q) starts[q] = k + j + 1;
    }
}

// Kernel B: one wave per edge. Coalesced token read, packed 4x16-bit register
// histogram (max seg len ~350 << 65535), 64-lane butterfly reduce, then each
// lane writes 2 channels: out[e] = (counts . emb) / max(total, 1).
__global__ __launch_bounds__(WAVES_PER_BLOCK * 64)
void edge_out_kernel(const int* __restrict__ tokens,
                     const int* __restrict__ starts,
                     const float* __restrict__ emb,
                     float* __restrict__ out,
                     int E) {
    const int lane = threadIdx.x & 63;
    const int wid  = threadIdx.x >> 6;
    const int e = blockIdx.x * WAVES_PER_BLOCK + wid;
    if (e >= E) return;

    const int start = starts[e];
    const int end   = starts[e + 1];

    unsigned long long acc = 0;
    for (int k = start + lane; k < end; k += 64) {
        acc += 1ull << (tokens[k] << 4);
    }
#pragma unroll
    for (int m = 32; m > 0; m >>= 1) {
        acc += __shfl_xor(acc, m, 64);
    }

    const float c0 = (float)(acc & 0xFFFFull);
    const float c1 = (float)((acc >> 16) & 0xFFFFull);
    const float c2 = (float)((acc >> 32) & 0xFFFFull);
    const float c3 = (float)((acc >> 48) & 0xFFFFull);
    const float tot = c0 + c1 + c2 + c3;
    const float inv = 1.0f / fmaxf(tot, 1.0f);

    const int c = lane << 1;
    const float2 e0 = *(const float2*)(emb + 0 * OUT_CH + c);
    const float2 e1 = *(const float2*)(emb + 1 * OUT_CH + c);
    const float2 e2 = *(const float2*)(emb + 2 * OUT_CH + c);
    const float2 e3 = *(const float2*)(emb + 3 * OUT_CH + c);

    float2 r;
    r.x = (c0 * e0.x + c1 * e1.x + c2 * e2.x + c3 * e3.x) * inv;
    r.y = (c0 * e0.y + c1 * e1.y + c2 * e2.y + c3 * e3.y) * inv;
    *(float2*)(out + (size_t)e * OUT_CH + c) = r;
}

extern "C" void kernel_launch(void* const* d_in, const int* in_sizes, int n_in,
                              void* d_out, int out_size, void* d_ws, size_t ws_size,
                              hipStream_t stream) {
    // inputs (setup_inputs order):
    // 0: overlap_similarity f32 [E]   (unused)
    // 1: overlap_length     f32 [E]   (unused)
    // 2: tokens             i32 [T]
    // 3: segment_ids        i32 [T]   (sorted)
    // 4: embedding          f32 [4,128]
    // 5: n_edges            i32 [1]   (device scalar; derive E from out_size)
    const int* tokens = (const int*)d_in[2];
    const int* segids = (const int*)d_in[3];
    const float* emb  = (const float*)d_in[4];
    float* out = (float*)d_out;

    const int T = in_sizes[2];
    const int E = out_size / OUT_CH;

    int* starts = (int*)d_ws;  // E+1 ints

    const int threadsA = (T + 3) / 4;
    const int blocksA = (threadsA + 255) / 256;
    seg_starts_kernel<<<blocksA, 256, 0, stream>>>(segids, starts, T, E);

    const int blocksB = (E + WAVES_PER_BLOCK - 1) / WAVES_PER_BLOCK;
    edge_out_kernel<<<blocksB, WAVES_PER_BLOCK * 64, 0, stream>>>(
        tokens, starts, emb, out, E);
}